// Round 1
// baseline (844.252 us; speedup 1.0000x reference)
//
#include <hip/hip_runtime.h>
#include <math.h>

#define TOKS 16384
#define HD   4096
#define NE   64      // experts
#define MT   64      // tokens per block
#define KT   64      // K tile
#define PKT  76      // padded LDS row: KT + 12 floats (16B-aligned, breaks conflicts)
#define NTHR 256

__global__ __launch_bounds__(NTHR) void router_kernel(
    const float* __restrict__ x, const float* __restrict__ W,
    float* __restrict__ scores, float* __restrict__ wout, float* __restrict__ iout)
{
    __shared__ float Xs[2][MT][PKT];
    __shared__ float Wsh[2][NE][PKT];
    __shared__ float Ls[MT][NE + 1];
    __shared__ float Ssum[MT];
    __shared__ float Smax[MT];

    const int t    = threadIdx.x;
    const int tok0 = blockIdx.x * MT;
    const int tx   = t & 15;   // expert group: experts tx + 16j
    const int ty   = t >> 4;   // token group:  tokens  ty + 16i
    const int srow = t >> 4;   // staging: row base, advances by 16 per iter
    const int sc4  = t & 15;   // staging: float4 column

    float acc[4][4];
#pragma unroll
    for (int i = 0; i < 4; ++i)
#pragma unroll
        for (int j = 0; j < 4; ++j) acc[i][j] = 0.f;

    float4 xr[4], wr[4];

    // prologue: stage tile 0
#pragma unroll
    for (int it = 0; it < 4; ++it) {
        const int row = srow + it * 16;
        xr[it] = *(const float4*)&x[(size_t)(tok0 + row) * HD + sc4 * 4];
        wr[it] = *(const float4*)&W[(size_t)row * HD + sc4 * 4];
    }
#pragma unroll
    for (int it = 0; it < 4; ++it) {
        const int row = srow + it * 16;
        *(float4*)&Xs[0][row][sc4 * 4]  = xr[it];
        *(float4*)&Wsh[0][row][sc4 * 4] = wr[it];
    }
    __syncthreads();

    const int NTILE = HD / KT;  // 64
    for (int tile = 0; tile < NTILE; ++tile) {
        const int cur = tile & 1;
        // prefetch tile+1 into registers (overlaps the compute below)
        if (tile + 1 < NTILE) {
            const int k0 = (tile + 1) * KT;
#pragma unroll
            for (int it = 0; it < 4; ++it) {
                const int row = srow + it * 16;
                xr[it] = *(const float4*)&x[(size_t)(tok0 + row) * HD + k0 + sc4 * 4];
                wr[it] = *(const float4*)&W[(size_t)row * HD + k0 + sc4 * 4];
            }
        }
#pragma unroll
        for (int k4 = 0; k4 < KT / 4; ++k4) {
            float4 xv[4], wv[4];
#pragma unroll
            for (int i = 0; i < 4; ++i) xv[i] = *(const float4*)&Xs[cur][ty + 16 * i][k4 * 4];
#pragma unroll
            for (int j = 0; j < 4; ++j) wv[j] = *(const float4*)&Wsh[cur][tx + 16 * j][k4 * 4];
#pragma unroll
            for (int i = 0; i < 4; ++i)
#pragma unroll
                for (int j = 0; j < 4; ++j)
                    acc[i][j] += xv[i].x * wv[j].x + xv[i].y * wv[j].y +
                                 xv[i].z * wv[j].z + xv[i].w * wv[j].w;
        }
        if (tile + 1 < NTILE) {
            const int nxt = cur ^ 1;
#pragma unroll
            for (int it = 0; it < 4; ++it) {
                const int row = srow + it * 16;
                *(float4*)&Xs[nxt][row][sc4 * 4]  = xr[it];
                *(float4*)&Wsh[nxt][row][sc4 * 4] = wr[it];
            }
        }
        __syncthreads();
    }

    // scatter logits to LDS for the per-token epilogue
#pragma unroll
    for (int i = 0; i < 4; ++i)
#pragma unroll
        for (int j = 0; j < 4; ++j)
            Ls[ty + 16 * i][tx + 16 * j] = acc[i][j];
    __syncthreads();

    if (t < MT) {
        const int tk = t;
        float m = -3.402823466e+38f;
        for (int e = 0; e < NE; ++e) m = fmaxf(m, Ls[tk][e]);
        float s  = 0.f;
        float v1 = -1.f, v2 = -1.f;  // exp(..) > 0 always
        int   i1 = 0, i2 = 0;
        for (int e = 0; e < NE; ++e) {
            const float ex = expf(Ls[tk][e] - m);
            s += ex;
            // strict > : first occurrence wins → matches lax.top_k tie-break
            if (ex > v1)      { v2 = v1; i2 = i1; v1 = ex; i1 = e; }
            else if (ex > v2) { v2 = ex; i2 = e; }
        }
        const float s1 = v1 / s, s2 = v2 / s;
        const float wsum = s1 + s2;
        wout[(size_t)(tok0 + tk) * 2 + 0] = s1 / wsum;
        wout[(size_t)(tok0 + tk) * 2 + 1] = s2 / wsum;
        iout[(size_t)(tok0 + tk) * 2 + 0] = (float)i1;
        iout[(size_t)(tok0 + tk) * 2 + 1] = (float)i2;
        Ssum[tk] = s;
        Smax[tk] = m;
    }
    __syncthreads();

    // coalesced scores write: 64 tokens x 64 experts per block
#pragma unroll
    for (int it = 0; it < 16; ++it) {
        const int f  = it * 256 + t;
        const int tk = f >> 6, e = f & 63;
        scores[(size_t)(tok0 + tk) * NE + e] = expf(Ls[tk][e] - Smax[tk]) / Ssum[tk];
    }
}

extern "C" void kernel_launch(void* const* d_in, const int* in_sizes, int n_in,
                              void* d_out, int out_size, void* d_ws, size_t ws_size,
                              hipStream_t stream) {
    (void)in_sizes; (void)n_in; (void)d_ws; (void)ws_size; (void)out_size;
    const float* x = (const float*)d_in[0];
    const float* W = (const float*)d_in[1];
    float* out    = (float*)d_out;
    float* scores = out;
    float* wout   = scores + (size_t)TOKS * NE;
    float* iout   = wout   + (size_t)TOKS * 2;
    router_kernel<<<dim3(TOKS / MT), dim3(NTHR), 0, stream>>>(x, W, scores, wout, iout);
}

// Round 2
// 393.036 us; speedup vs baseline: 2.1480x; 2.1480x over previous
//
#include <hip/hip_runtime.h>
#include <math.h>

#define TOKS 16384
#define HD   4096
#define NE   64
#define MT   64          // tokens per block
#define KT   64          // K tile
#define NTHR 512
#define LST  72          // LDS row stride in bf16 elems (64 + 8 pad -> 2-way max conflicts)

typedef unsigned int   u32;
typedef unsigned short u16;
typedef short v8s __attribute__((ext_vector_type(8)));   // 8 bf16 (4 VGPRs)
typedef float v4f __attribute__((ext_vector_type(4)));   // 4 fp32 acc

// exact split: a = hi(a) + lo_f(a); hi/lo truncated to bf16 (error ~2^-16 rel)
__device__ __forceinline__ void split2(float a, float b, u32& hi, u32& lo) {
    u32 ua = __float_as_uint(a), ub = __float_as_uint(b);
    hi = (ub & 0xffff0000u) | (ua >> 16);
    float la = a - __uint_as_float(ua & 0xffff0000u);
    float lb = b - __uint_as_float(ub & 0xffff0000u);
    lo = (__float_as_uint(lb) & 0xffff0000u) | (__float_as_uint(la) >> 16);
}

// Pre-pass: split W [NE][HD] fp32 -> Whi, Wlo bf16 (row-major, same indexing)
__global__ __launch_bounds__(256) void wsplit_kernel(const float* __restrict__ W,
                                                     u16* __restrict__ wh, u16* __restrict__ wl) {
    const int gid = blockIdx.x * 256 + threadIdx.x;     // 65536 threads, one float4 each
    const float4 f = ((const float4*)W)[gid];
    u32 h0, h1, l0, l1;
    split2(f.x, f.y, h0, l0);
    split2(f.z, f.w, h1, l1);
    u32* whp = (u32*)wh; u32* wlp = (u32*)wl;
    whp[gid * 2 + 0] = h0; whp[gid * 2 + 1] = h1;
    wlp[gid * 2 + 0] = l0; wlp[gid * 2 + 1] = l1;
}

__global__ __launch_bounds__(NTHR) void router_kernel(
    const float* __restrict__ x, const u16* __restrict__ wh, const u16* __restrict__ wl,
    float* __restrict__ scores, float* __restrict__ wout, float* __restrict__ iout)
{
    __shared__ u16 Xh[2][MT][LST], Xl[2][MT][LST];
    __shared__ u16 Wh[2][NE][LST], Wl[2][NE][LST];
    __shared__ float Ls[MT][NE + 1];
    __shared__ float Ssum[MT], Smax[MT];

    const int t    = threadIdx.x;
    const int tok0 = blockIdx.x * MT;
    // staging mapping: 64 rows x 8 columns of threads
    const int srow = t >> 3;          // 0..63 (token row for X, expert row for W)
    const int sc   = t & 7;           // 0..7
    // compute mapping: wave w: token group wt (16 tokens), expert half we (32 experts)
    const int lane = t & 63;
    const int w    = t >> 6;          // 0..7
    const int wt   = w & 3;
    const int we   = w >> 1 & 2 ? 0 : 0; // placeholder (unused)
    const int weh  = w >> 2;          // 0..1
    const int q    = lane >> 4;       // 0..3
    const int r    = lane & 15;

    v4f acc0 = {0.f, 0.f, 0.f, 0.f};
    v4f acc1 = {0.f, 0.f, 0.f, 0.f};

    const size_t xbase = (size_t)(tok0 + srow) * HD;
    const size_t wbase = (size_t)srow * HD;

    float4 xr0, xr1; uint4 whr, wlr;

    // prologue: stage tile 0 into registers
    {
        const int k0 = 0;
        xr0 = *(const float4*)&x[xbase + k0 + sc * 4];
        xr1 = *(const float4*)&x[xbase + k0 + 32 + sc * 4];
        whr = *(const uint4*)&wh[wbase + k0 + sc * 8];
        wlr = *(const uint4*)&wl[wbase + k0 + sc * 8];
    }

    const int arow  = wt * 16 + r;
    const int brow0 = weh * 32 + r;
    const int brow1 = weh * 32 + 16 + r;

    for (int tile = 0; tile < HD / KT; ++tile) {
        const int buf = tile & 1;
        // ---- convert + store staged regs to LDS[buf] ----
        {
            u32 h0, h1, l0, l1;
            split2(xr0.x, xr0.y, h0, l0);
            split2(xr0.z, xr0.w, h1, l1);
            *(u32*)&Xh[buf][srow][sc * 4]     = h0; *(u32*)&Xh[buf][srow][sc * 4 + 2] = h1;
            *(u32*)&Xl[buf][srow][sc * 4]     = l0; *(u32*)&Xl[buf][srow][sc * 4 + 2] = l1;
            split2(xr1.x, xr1.y, h0, l0);
            split2(xr1.z, xr1.w, h1, l1);
            *(u32*)&Xh[buf][srow][32 + sc * 4]     = h0; *(u32*)&Xh[buf][srow][32 + sc * 4 + 2] = h1;
            *(u32*)&Xl[buf][srow][32 + sc * 4]     = l0; *(u32*)&Xl[buf][srow][32 + sc * 4 + 2] = l1;
            *(uint4*)&Wh[buf][srow][sc * 8] = whr;
            *(uint4*)&Wl[buf][srow][sc * 8] = wlr;
        }
        // ---- prefetch next tile into registers (in flight across barrier+compute) ----
        if (tile + 1 < HD / KT) {
            const int k0 = (tile + 1) * KT;
            xr0 = *(const float4*)&x[xbase + k0 + sc * 4];
            xr1 = *(const float4*)&x[xbase + k0 + 32 + sc * 4];
            whr = *(const uint4*)&wh[wbase + k0 + sc * 8];
            wlr = *(const uint4*)&wl[wbase + k0 + sc * 8];
        }
        __syncthreads();
        // ---- MFMA compute on LDS[buf]: 2 k-chunks of 32 ----
#pragma unroll
        for (int c = 0; c < 2; ++c) {
            const int ko = c * 32 + q * 8;
            v8s ah  = *(const v8s*)&Xh[buf][arow][ko];
            v8s al  = *(const v8s*)&Xl[buf][arow][ko];
            v8s bh0 = *(const v8s*)&Wh[buf][brow0][ko];
            v8s bl0 = *(const v8s*)&Wl[buf][brow0][ko];
            v8s bh1 = *(const v8s*)&Wh[buf][brow1][ko];
            v8s bl1 = *(const v8s*)&Wl[buf][brow1][ko];
            acc0 = __builtin_amdgcn_mfma_f32_16x16x32_bf16(ah, bh0, acc0, 0, 0, 0);
            acc0 = __builtin_amdgcn_mfma_f32_16x16x32_bf16(al, bh0, acc0, 0, 0, 0);
            acc0 = __builtin_amdgcn_mfma_f32_16x16x32_bf16(ah, bl0, acc0, 0, 0, 0);
            acc1 = __builtin_amdgcn_mfma_f32_16x16x32_bf16(ah, bh1, acc1, 0, 0, 0);
            acc1 = __builtin_amdgcn_mfma_f32_16x16x32_bf16(al, bh1, acc1, 0, 0, 0);
            acc1 = __builtin_amdgcn_mfma_f32_16x16x32_bf16(ah, bl1, acc1, 0, 0, 0);
        }
        __syncthreads();
    }

    // ---- scatter logits to LDS (D layout: col=lane&15, row=q*4+reg) ----
#pragma unroll
    for (int reg = 0; reg < 4; ++reg) {
        Ls[wt * 16 + q * 4 + reg][weh * 32 + r]      = acc0[reg];
        Ls[wt * 16 + q * 4 + reg][weh * 32 + 16 + r] = acc1[reg];
    }
    __syncthreads();

    // ---- per-token softmax + top-2 (verified in round 1) ----
    if (t < MT) {
        const int tk = t;
        float m = -3.402823466e+38f;
        for (int e = 0; e < NE; ++e) m = fmaxf(m, Ls[tk][e]);
        float s = 0.f;
        float v1 = -1.f, v2 = -1.f;
        int   i1 = 0, i2 = 0;
        for (int e = 0; e < NE; ++e) {
            const float ex = expf(Ls[tk][e] - m);
            s += ex;
            if (ex > v1)      { v2 = v1; i2 = i1; v1 = ex; i1 = e; }
            else if (ex > v2) { v2 = ex; i2 = e; }
        }
        const float s1 = v1 / s, s2 = v2 / s;
        const float ws_ = s1 + s2;
        wout[(size_t)(tok0 + tk) * 2 + 0] = s1 / ws_;
        wout[(size_t)(tok0 + tk) * 2 + 1] = s2 / ws_;
        iout[(size_t)(tok0 + tk) * 2 + 0] = (float)i1;
        iout[(size_t)(tok0 + tk) * 2 + 1] = (float)i2;
        Ssum[tk] = s;
        Smax[tk] = m;
    }
    __syncthreads();

    // ---- coalesced scores write: 4096 elems / 512 threads ----
#pragma unroll
    for (int it = 0; it < 8; ++it) {
        const int f  = it * NTHR + t;
        const int tk = f >> 6, e = f & 63;
        scores[(size_t)(tok0 + tk) * NE + e] = expf(Ls[tk][e] - Smax[tk]) / Ssum[tk];
    }
}

extern "C" void kernel_launch(void* const* d_in, const int* in_sizes, int n_in,
                              void* d_out, int out_size, void* d_ws, size_t ws_size,
                              hipStream_t stream) {
    (void)in_sizes; (void)n_in; (void)out_size; (void)ws_size;
    const float* x = (const float*)d_in[0];
    const float* W = (const float*)d_in[1];
    float* out    = (float*)d_out;
    float* scores = out;
    float* wout   = scores + (size_t)TOKS * NE;
    float* iout   = wout   + (size_t)TOKS * 2;

    u16* wh = (u16*)d_ws;                       // [NE][HD] bf16 hi
    u16* wl = wh + (size_t)NE * HD;             // [NE][HD] bf16 lo

    wsplit_kernel<<<dim3(256), dim3(256), 0, stream>>>(W, wh, wl);
    router_kernel<<<dim3(TOKS / MT), dim3(NTHR), 0, stream>>>(x, wh, wl, scores, wout, iout);
}

// Round 3
// 392.511 us; speedup vs baseline: 2.1509x; 1.0013x over previous
//
#include <hip/hip_runtime.h>
#include <math.h>

#define TOKS  16384
#define HD    4096
#define NE    64
#define MT    32          // tokens per block
#define KT    64          // K tile
#define NTHR  256         // 4 waves
#define LST   72          // LDS row stride in bf16 (64 + 8 pad)
#define NTILE (HD / KT)   // 64

typedef unsigned int   u32;
typedef unsigned short u16;
typedef short v8s __attribute__((ext_vector_type(8)));   // 8 bf16
typedef float v4f __attribute__((ext_vector_type(4)));   // 4 fp32

// exact split: a ≈ hi + lo, both bf16 (truncation); residual ~2^-17 rel
__device__ __forceinline__ void split2(float a, float b, u32& hi, u32& lo) {
    u32 ua = __float_as_uint(a), ub = __float_as_uint(b);
    hi = (ub & 0xffff0000u) | (ua >> 16);
    float la = a - __uint_as_float(ua & 0xffff0000u);
    float lb = b - __uint_as_float(ub & 0xffff0000u);
    lo = (__float_as_uint(lb) & 0xffff0000u) | (__float_as_uint(la) >> 16);
}

// Pre-pass: split W [NE][HD] fp32 -> bf16 hi/lo planes in d_ws
__global__ __launch_bounds__(256) void wsplit_kernel(const float* __restrict__ W,
                                                     u16* __restrict__ wh, u16* __restrict__ wl) {
    const int gid = blockIdx.x * 256 + threadIdx.x;   // 65536 threads, one float4 each
    const float4 f = ((const float4*)W)[gid];
    u32 h0, h1, l0, l1;
    split2(f.x, f.y, h0, l0);
    split2(f.z, f.w, h1, l1);
    u32* whp = (u32*)wh; u32* wlp = (u32*)wl;
    whp[gid * 2 + 0] = h0; whp[gid * 2 + 1] = h1;
    wlp[gid * 2 + 0] = l0; wlp[gid * 2 + 1] = l1;
}

__global__ __launch_bounds__(NTHR, 2) void router_kernel(
    const float* __restrict__ x, const u16* __restrict__ wh, const u16* __restrict__ wl,
    float* __restrict__ scores, float* __restrict__ wout, float* __restrict__ iout)
{
    __shared__ u16 Xh[2][MT][LST], Xl[2][MT][LST];
    __shared__ u16 Wh[2][NE][LST], Wl[2][NE][LST];
    __shared__ float Ls[MT][NE + 1];
    __shared__ float Ssum[MT], Smax[MT];

    const int t    = threadIdx.x;
    const int tok0 = blockIdx.x * MT;
    // X staging: 32 rows x 8 float4-cols
    const int srow = t >> 3, sc = t & 7;
    // W staging: 64 rows x 4 uint4-cols (two segments per row)
    const int wrow = t >> 2, wc = t & 3;
    // compute mapping
    const int lane = t & 63;
    const int w    = t >> 6;          // 0..3
    const int wt   = w & 1;           // token group (16)
    const int weh  = w >> 1;          // expert half (32)
    const int q    = lane >> 4, r = lane & 15;
    const int arow  = wt * 16 + r;
    const int brow0 = weh * 32 + r;
    const int brow1 = weh * 32 + 16 + r;

    v4f acc0 = {0.f, 0.f, 0.f, 0.f};
    v4f acc1 = {0.f, 0.f, 0.f, 0.f};

    const size_t xbase = (size_t)(tok0 + srow) * HD;
    const size_t wbase = (size_t)wrow * HD;

    float4 xr0, xr1;
    uint4  whr0, whr1, wlr0, wlr1;

#define LOAD_TILE(K0)                                               \
    do {                                                            \
        xr0  = *(const float4*)&x[xbase + (K0) + sc * 4];           \
        xr1  = *(const float4*)&x[xbase + (K0) + 32 + sc * 4];      \
        whr0 = *(const uint4*)&wh[wbase + (K0) + wc * 8];           \
        whr1 = *(const uint4*)&wh[wbase + (K0) + 32 + wc * 8];      \
        wlr0 = *(const uint4*)&wl[wbase + (K0) + wc * 8];           \
        wlr1 = *(const uint4*)&wl[wbase + (K0) + 32 + wc * 8];      \
    } while (0)

#define STORE_TILE(B)                                               \
    do {                                                            \
        u32 h0, h1, l0, l1;                                         \
        split2(xr0.x, xr0.y, h0, l0);                               \
        split2(xr0.z, xr0.w, h1, l1);                               \
        *(uint2*)&Xh[B][srow][sc * 4]      = make_uint2(h0, h1);    \
        *(uint2*)&Xl[B][srow][sc * 4]      = make_uint2(l0, l1);    \
        split2(xr1.x, xr1.y, h0, l0);                               \
        split2(xr1.z, xr1.w, h1, l1);                               \
        *(uint2*)&Xh[B][srow][32 + sc * 4] = make_uint2(h0, h1);    \
        *(uint2*)&Xl[B][srow][32 + sc * 4] = make_uint2(l0, l1);    \
        *(uint4*)&Wh[B][wrow][wc * 8]      = whr0;                  \
        *(uint4*)&Wh[B][wrow][32 + wc * 8] = whr1;                  \
        *(uint4*)&Wl[B][wrow][wc * 8]      = wlr0;                  \
        *(uint4*)&Wl[B][wrow][32 + wc * 8] = wlr1;                  \
    } while (0)

    // prologue: tile 0 -> LDS[0]
    LOAD_TILE(0);
    STORE_TILE(0);
    __syncthreads();

    for (int tile = 0; tile < NTILE; ++tile) {
        const int buf = tile & 1;
        if (tile + 1 < NTILE) LOAD_TILE((tile + 1) * KT);
        // compute on LDS[buf]
#pragma unroll
        for (int c = 0; c < 2; ++c) {
            const int ko = c * 32 + q * 8;
            v8s ah  = *(const v8s*)&Xh[buf][arow][ko];
            v8s al  = *(const v8s*)&Xl[buf][arow][ko];
            v8s bh0 = *(const v8s*)&Wh[buf][brow0][ko];
            v8s bl0 = *(const v8s*)&Wl[buf][brow0][ko];
            v8s bh1 = *(const v8s*)&Wh[buf][brow1][ko];
            v8s bl1 = *(const v8s*)&Wl[buf][brow1][ko];
            acc0 = __builtin_amdgcn_mfma_f32_16x16x32_bf16(ah, bh0, acc0, 0, 0, 0);
            acc0 = __builtin_amdgcn_mfma_f32_16x16x32_bf16(al, bh0, acc0, 0, 0, 0);
            acc0 = __builtin_amdgcn_mfma_f32_16x16x32_bf16(ah, bl0, acc0, 0, 0, 0);
            acc1 = __builtin_amdgcn_mfma_f32_16x16x32_bf16(ah, bh1, acc1, 0, 0, 0);
            acc1 = __builtin_amdgcn_mfma_f32_16x16x32_bf16(al, bh1, acc1, 0, 0, 0);
            acc1 = __builtin_amdgcn_mfma_f32_16x16x32_bf16(ah, bl1, acc1, 0, 0, 0);
        }
        if (tile + 1 < NTILE) STORE_TILE(buf ^ 1);   // write the OTHER buffer: no intra-iter race
        __syncthreads();                             // single barrier per tile
    }

    // scatter logits (D layout: col = lane&15, row = q*4 + reg)
#pragma unroll
    for (int reg = 0; reg < 4; ++reg) {
        Ls[wt * 16 + q * 4 + reg][weh * 32 + r]      = acc0[reg];
        Ls[wt * 16 + q * 4 + reg][weh * 32 + 16 + r] = acc1[reg];
    }
    __syncthreads();

    if (t < MT) {
        const int tk = t;
        float m = -3.402823466e+38f;
        for (int e = 0; e < NE; ++e) m = fmaxf(m, Ls[tk][e]);
        float s = 0.f;
        float v1 = -1.f, v2 = -1.f;
        int   i1 = 0, i2 = 0;
        for (int e = 0; e < NE; ++e) {
            const float ex = expf(Ls[tk][e] - m);
            s += ex;
            if (ex > v1)      { v2 = v1; i2 = i1; v1 = ex; i1 = e; }
            else if (ex > v2) { v2 = ex; i2 = e; }
        }
        const float s1 = v1 / s, s2 = v2 / s;
        const float ws_ = s1 + s2;
        wout[(size_t)(tok0 + tk) * 2 + 0] = s1 / ws_;
        wout[(size_t)(tok0 + tk) * 2 + 1] = s2 / ws_;
        iout[(size_t)(tok0 + tk) * 2 + 0] = (float)i1;
        iout[(size_t)(tok0 + tk) * 2 + 1] = (float)i2;
        Ssum[tk] = s;
        Smax[tk] = m;
    }
    __syncthreads();

    // coalesced scores write: 32*64 = 2048 elems / 256 threads
#pragma unroll
    for (int it = 0; it < (MT * NE) / NTHR; ++it) {
        const int f  = it * NTHR + t;
        const int tk = f >> 6, e = f & 63;
        scores[(size_t)(tok0 + tk) * NE + e] = expf(Ls[tk][e] - Smax[tk]) / Ssum[tk];
    }
}

extern "C" void kernel_launch(void* const* d_in, const int* in_sizes, int n_in,
                              void* d_out, int out_size, void* d_ws, size_t ws_size,
                              hipStream_t stream) {
    (void)in_sizes; (void)n_in; (void)out_size; (void)ws_size;
    const float* x = (const float*)d_in[0];
    const float* W = (const float*)d_in[1];
    float* out    = (float*)d_out;
    float* scores = out;
    float* wout   = scores + (size_t)TOKS * NE;
    float* iout   = wout   + (size_t)TOKS * 2;

    u16* wh = (u16*)d_ws;
    u16* wl = wh + (size_t)NE * HD;

    wsplit_kernel<<<dim3(256), dim3(256), 0, stream>>>(W, wh, wl);
    router_kernel<<<dim3(TOKS / MT), dim3(NTHR), 0, stream>>>(x, wh, wl, scores, wout, iout);
}